// Round 5
// baseline (6732.505 us; speedup 1.0000x reference)
//
#include <hip/hip_runtime.h>
#include <cstdint>
#include <cstddef>

typedef unsigned short u16;
typedef __attribute__((ext_vector_type(8))) short short8;
typedef __attribute__((ext_vector_type(4))) float f32x4;

#define XT_HSTRIDE 18432      /* 2*36*256 */
#define XT_BSTRIDE 1308672    /* 71*18432 */
#define K_TOT 20736
#define N_TOT 32768
#define M_TOT 1024
#define K_STEPS 648           /* 20736 / 32 */
#define GRP 512               /* elements per 16-row LDS group (4 chunks x 16 rows x 8) */

__device__ __forceinline__ u16 f2bf(float f) {
  uint32_t u = __builtin_bit_cast(uint32_t, f);
  u = (u + 0x7fffu + ((u >> 16) & 1u)) >> 16;
  return (u16)u;
}
__device__ __forceinline__ float bf2f(u16 h) {
  uint32_t u = ((uint32_t)h) << 16;
  return __builtin_bit_cast(float, u);
}

// ---- pack weights: Wb[m][pos*256+c] = bf16(W[m][c][kh][kw]) ----
__global__ __launch_bounds__(256) void pack_w(const float* __restrict__ W,
                                              u16* __restrict__ Wb) {
  __shared__ u16 wl[20736];
  const int m = blockIdx.x;
  const int t = threadIdx.x;
  const size_t base = (size_t)m * K_TOT;
  for (int i = t; i < K_TOT; i += 256) {
    float f = W[base + i];          // input layout per m: (c, pos), i = c*81+pos
    int c = i / 81;
    int pos = i - c * 81;
    wl[pos * 256 + c] = f2bf(f);
  }
  __syncthreads();
  for (int i = t; i < K_TOT; i += 256) Wb[base + i] = wl[i];
}

// ---- pack x: xT[b][h][par][j][c] = bf16(x[b][c][h][2j+par]) ----
__global__ __launch_bounds__(256) void pack_x(const float* __restrict__ X,
                                              u16* __restrict__ xT) {
  __shared__ u16 xl[256 * 73];
  const int h = blockIdx.x;   // 0..70
  const int b = blockIdx.y;   // 0..31
  const int t = threadIdx.x;  // = c on write phase
  for (int i = t; i < 256 * 71; i += 256) {
    int c = i / 71;
    int w = i - c * 71;
    float f = X[(((size_t)(b * 256 + c)) * 71 + h) * 71 + w];
    xl[c * 73 + w] = f2bf(f);
  }
  __syncthreads();
  const size_t obase = (size_t)b * XT_BSTRIDE + (size_t)h * XT_HSTRIDE;
  for (int s = 0; s < 71; ++s) {
    int par = (s >= 36) ? 1 : 0;
    int j = s - par * 36;
    int w = 2 * j + par;
    xT[obase + par * 9216 + j * 256 + t] = xl[t * 73 + w];
  }
}

// ---- conv as implicit GEMM: U[n][m] = sum_k Wb[m][k] * X[n][k] ----
// Round-1 proven skeleton: block 128m x 128n, BK=32, 4 waves 2x2, wave
// tile 64x64 of 16x16x32 MFMA. m0=(bx&7)*128 pins m-tile == XCD.
// Fix 1: conflict-free LDS (group g of 16 rows at g*GRP; slot =
//        chunk*16 + row%16; frag read = groupbase + lane*16B).
// Fix 2: prefetch t+1's 4 global loads after barrier 2, before compute(t).
// Fix 3: U stored [n][m] with packed uint2 stores for coalesced routing.
__global__ __launch_bounds__(256, 2) void conv_gemm(const u16* __restrict__ Wb,
                                                    const u16* __restrict__ xT,
                                                    u16* __restrict__ U) {
  __shared__ __align__(16) u16 As[128 * 32];   // 8KB = 8 groups
  __shared__ __align__(16) u16 Bs[128 * 32];   // 8KB = 8 groups
  const int tid = threadIdx.x;
  const int bx = blockIdx.x;
  const int m0 = (bx & 7) * 128;
  const int n0 = (bx >> 3) * 128;
  const int lane = tid & 63;
  const int wave = tid >> 6;
  const int wm = wave >> 1;   // 0..1
  const int wn = wave & 1;    // 0..1

  // staging: thread -> (row = slot*64 + tid>>2, k8-chunk = tid&3)
  const int srow = tid >> 2;
  const int sq = (tid & 3) * 8;

  const u16* aP[2];
  const u16* bP[2];
  int wi[2];
#pragma unroll
  for (int s = 0; s < 2; ++s) {
    const int row = s * 64 + srow;
    aP[s] = Wb + (size_t)(m0 + row) * K_TOT + sq;
    const int ng = n0 + row;
    const size_t nb = (size_t)(ng >> 10) * XT_BSTRIDE +
                      (size_t)(((ng >> 5) & 31) * 2) * XT_HSTRIDE + (size_t)(ng & 31) * 256;
    bP[s] = xT + nb + sq;
    wi[s] = (row >> 4) * GRP + ((tid & 3) * 16 + (row & 15)) * 8;
  }

  f32x4 acc[4][4];
#pragma unroll
  for (int i = 0; i < 4; ++i)
#pragma unroll
    for (int j = 0; j < 4; ++j) acc[i][j] = (f32x4){0.f, 0.f, 0.f, 0.f};

  // fragment read offsets (elements): A frag i at (wm*4+i)*GRP + lane*8
  const int fra = (wm * 4) * GRP + lane * 8;
  const int frb = (wn * 4) * GRP + lane * 8;

  // B global k-offset for step t  (k = p*256 + (t&7)*32, p = kh*9+kw)
  auto koffB = [](int t) {
    const int p = t >> 3;
    const int kh = p / 9;
    const int kw = p - kh * 9;
    return kh * XT_HSTRIDE + (kw & 1) * 9216 + (kw >> 1) * 256 + (t & 7) * 32;
  };

  uint4 ra[2], rb[2];
#pragma unroll
  for (int s = 0; s < 2; ++s) ra[s] = *(const uint4*)(aP[s]);
  {
    const int kb = koffB(0);
#pragma unroll
    for (int s = 0; s < 2; ++s) rb[s] = *(const uint4*)(bP[s] + kb);
  }

  for (int t = 0; t < K_STEPS; ++t) {
    __syncthreads();
#pragma unroll
    for (int s = 0; s < 2; ++s) *(uint4*)&As[wi[s]] = ra[s];
#pragma unroll
    for (int s = 0; s < 2; ++s) *(uint4*)&Bs[wi[s]] = rb[s];
    __syncthreads();
    if (t + 1 < K_STEPS) {
      const int ka = (t + 1) * 32;
      const int kb = koffB(t + 1);
#pragma unroll
      for (int s = 0; s < 2; ++s) ra[s] = *(const uint4*)(aP[s] + ka);
#pragma unroll
      for (int s = 0; s < 2; ++s) rb[s] = *(const uint4*)(bP[s] + kb);
    }
    short8 af[4], bf[4];
#pragma unroll
    for (int i = 0; i < 4; ++i) af[i] = *(const short8*)&As[fra + i * GRP];
#pragma unroll
    for (int j = 0; j < 4; ++j) bf[j] = *(const short8*)&Bs[frb + j * GRP];
#pragma unroll
    for (int i = 0; i < 4; ++i)
#pragma unroll
      for (int j = 0; j < 4; ++j)
        acc[i][j] = __builtin_amdgcn_mfma_f32_16x16x32_bf16(af[i], bf[j], acc[i][j], 0, 0, 0);
  }

  // C/D 16x16: col = lane&15 (n-local), row = (lane>>4)*4 + reg (m-local)
  // regs 0..3 are m-consecutive -> pack into one 8B store to U[n][m].
  const int cn = lane & 15;
  const int r0 = (lane >> 4) * 4;
#pragma unroll
  for (int i = 0; i < 4; ++i) {
    const int mg = m0 + wm * 64 + i * 16 + r0;
#pragma unroll
    for (int j = 0; j < 4; ++j) {
      const int ng = n0 + wn * 64 + j * 16 + cn;
      uint2 pk;
      pk.x = (uint32_t)f2bf(acc[i][j][0]) | ((uint32_t)f2bf(acc[i][j][1]) << 16);
      pk.y = (uint32_t)f2bf(acc[i][j][2]) | ((uint32_t)f2bf(acc[i][j][3]) << 16);
      *(uint2*)(U + (size_t)ng * M_TOT + mg) = pk;
    }
  }
}

// ---- dynamic routing: one block per (b,hp); thread = (nc,oc) ----
// U is [n][m]: per-wp loads are fully coalesced across the 1024 threads.
__global__ __launch_bounds__(1024) void routing_k(const u16* __restrict__ U,
                                                  const float* __restrict__ bias,
                                                  float* __restrict__ out) {
  const int t = threadIdx.x;       // m = nc*32 + oc
  const int bx = blockIdx.x;
  const int b = bx >> 5;
  const int hp = bx & 31;
  const int oc = t & 31;
  const int nc = t >> 5;
  __shared__ float sm[1024];

  float u_r[32];
  {
    const u16* ub = U + (size_t)(b * 1024 + hp * 32) * M_TOT + t;
    const float bs = bias[t];
#pragma unroll
    for (int w = 0; w < 32; ++w) u_r[w] = bf2f(ub[(size_t)w * M_TOT]) + bs;
  }

  float bij = 0.f;
  float s[32];
  float scale = 0.f;

  for (int it = 0; it < 3; ++it) {
    sm[t] = bij;
    __syncthreads();
    // softmax over nc for this oc (values are small; no max-subtract needed)
    float den = 0.f;
#pragma unroll
    for (int i = 0; i < 32; ++i) den += __expf(sm[i * 32 + oc]);
    const float c = __expf(bij) / den;
    // s[nc][wp] = sum_oc c*u_hat : butterfly allreduce across the 32-lane oc group
#pragma unroll
    for (int w = 0; w < 32; ++w) s[w] = c * u_r[w];
#pragma unroll
    for (int off = 1; off < 32; off <<= 1) {
#pragma unroll
      for (int w = 0; w < 32; ++w) s[w] += __shfl_xor(s[w], off, 64);
    }
    // squash over wp
    float n2 = 0.f;
#pragma unroll
    for (int w = 0; w < 32; ++w) n2 += s[w] * s[w];
    scale = sqrtf(n2) / (1.f + n2);
    if (it < 2) {
      // b_ij += sum_wp u_hat * v ;  v = scale*s
      float agr = 0.f;
#pragma unroll
      for (int w = 0; w < 32; ++w) agr += u_r[w] * s[w];
      bij += scale * agr;
    }
    __syncthreads();
  }

  // lane oc writes element wp==oc (register-select to avoid scratch)
  float val = s[0];
#pragma unroll
  for (int i = 1; i < 32; ++i) val = (oc == i) ? s[i] : val;
  out[(size_t)((b * 32 + nc) * 32 + hp) * 32 + oc] = scale * val;
}

extern "C" void kernel_launch(void* const* d_in, const int* in_sizes, int n_in,
                              void* d_out, int out_size, void* d_ws, size_t ws_size,
                              hipStream_t stream) {
  const float* x = (const float*)d_in[0];
  const float* W = (const float*)d_in[1];
  const float* bias = (const float*)d_in[2];

  // workspace layout (bytes): Wb 42,467,328 | xT 83,755,008 | U 67,108,864  (total 193.3 MB)
  u16* Wb = (u16*)d_ws;
  u16* xT = (u16*)((char*)d_ws + 42467328u);
  u16* U  = (u16*)((char*)d_ws + 126222336u);
  float* out = (float*)d_out;

  pack_w<<<dim3(1024), dim3(256), 0, stream>>>(W, Wb);
  pack_x<<<dim3(71, 32), dim3(256), 0, stream>>>(x, xT);
  conv_gemm<<<dim3(2048), dim3(256), 0, stream>>>(Wb, xT, U);
  routing_k<<<dim3(1024), dim3(1024), 0, stream>>>(U, bias, out);
}

// Round 6
// 2518.718 us; speedup vs baseline: 2.6730x; 2.6730x over previous
//
#include <hip/hip_runtime.h>
#include <cstdint>
#include <cstddef>

typedef unsigned short u16;
typedef __attribute__((ext_vector_type(8))) short short8;
typedef __attribute__((ext_vector_type(4))) float f32x4;

#define XT_HSTRIDE 18432      /* 2*36*256 */
#define XT_BSTRIDE 1308672    /* 71*18432 */
#define K_TOT 20736
#define N_TOT 32768
#define M_TOT 1024
#define K_STEPS 648           /* 20736 / 32 */

__device__ __forceinline__ u16 f2bf(float f) {
  uint32_t u = __builtin_bit_cast(uint32_t, f);
  u = (u + 0x7fffu + ((u >> 16) & 1u)) >> 16;
  return (u16)u;
}
__device__ __forceinline__ float bf2f(u16 h) {
  uint32_t u = ((uint32_t)h) << 16;
  return __builtin_bit_cast(float, u);
}
__device__ __forceinline__ void glds16(const void* g, void* l) {
  __builtin_amdgcn_global_load_lds((const __attribute__((address_space(1))) void*)g,
                                   (__attribute__((address_space(3))) void*)l, 16, 0, 0);
}

// ---- pack weights: Wb[m][pos*256+c] = bf16(W[m][c][kh][kw]) ----
__global__ __launch_bounds__(256) void pack_w(const float* __restrict__ W,
                                              u16* __restrict__ Wb) {
  __shared__ u16 wl[20736];
  const int m = blockIdx.x;
  const int t = threadIdx.x;
  const size_t base = (size_t)m * K_TOT;
  for (int i = t; i < K_TOT; i += 256) {
    float f = W[base + i];          // input layout per m: (c, pos), i = c*81+pos
    int c = i / 81;
    int pos = i - c * 81;
    wl[pos * 256 + c] = f2bf(f);
  }
  __syncthreads();
  for (int i = t; i < K_TOT; i += 256) Wb[base + i] = wl[i];
}

// ---- pack x: xT[b][h][par][j][c] = bf16(x[b][c][h][2j+par]) ----
__global__ __launch_bounds__(256) void pack_x(const float* __restrict__ X,
                                              u16* __restrict__ xT) {
  __shared__ u16 xl[256 * 73];
  const int h = blockIdx.x;   // 0..70
  const int b = blockIdx.y;   // 0..31
  const int t = threadIdx.x;  // = c on write phase
  for (int i = t; i < 256 * 71; i += 256) {
    int c = i / 71;
    int w = i - c * 71;
    float f = X[(((size_t)(b * 256 + c)) * 71 + h) * 71 + w];
    xl[c * 73 + w] = f2bf(f);
  }
  __syncthreads();
  const size_t obase = (size_t)b * XT_BSTRIDE + (size_t)h * XT_HSTRIDE;
  for (int s = 0; s < 71; ++s) {
    int par = (s >= 36) ? 1 : 0;
    int j = s - par * 36;
    int w = 2 * j + par;
    xT[obase + par * 9216 + j * 256 + t] = xl[t * 73 + w];
  }
}

// ---- conv as implicit GEMM: U[n][m] = sum_k Wb[m][k] * X[n][k] ----
// Block 128m x 128n, BK=32, 4 waves 2x2, wave tile 64x64 of 16x16x32 MFMA.
// m0=(bx&7)*128 pins the 5.3MB A slice to one XCD's L2.
// Staging: double-buffered global_load_lds width=16 (NO staging VGPRs ->
// nothing for the compiler to spill; r4/r5's 13-16GB scratch traffic came
// from register prefetch held across barriers).
// One barrier per K-step: glds(t+1 -> nxt) issued first, compute(t) on cur
// hides the load latency, __syncthreads() drains vmcnt before buffers swap.
// LDS layout: natural row-major [row][32] (glds requires base + lane*16B;
// writes are conflict-free, reads carry r1's known 1.7e8 conflict cycles).
__global__ __launch_bounds__(256) void conv_gemm(const u16* __restrict__ Wb,
                                                 const u16* __restrict__ xT,
                                                 u16* __restrict__ U) {
  __shared__ __align__(16) u16 As[2][128 * 32];   // 2 x 8KB
  __shared__ __align__(16) u16 Bs[2][128 * 32];   // 2 x 8KB
  const int tid = threadIdx.x;
  const int bx = blockIdx.x;
  const int m0 = (bx & 7) * 128;
  const int n0 = (bx >> 3) * 128;
  const int lane = tid & 63;
  const int wave = tid >> 6;
  const int wm = wave >> 1;   // 0..1
  const int wn = wave & 1;    // 0..1

  // glds staging: wave covers rows s*64 + wave*16 + (lane>>2), chunk (lane&3)*8.
  // LDS dest el = rowbase*32 + lane*8  (wave-uniform base + lane*16B).
  const int srow = lane >> 2;
  const int skq = (lane & 3) * 8;
  const u16* aG[2];
  const u16* bG[2];
  int ldsOff[2];
#pragma unroll
  for (int s = 0; s < 2; ++s) {
    const int row = s * 64 + wave * 16 + srow;
    aG[s] = Wb + (size_t)(m0 + row) * K_TOT + skq;
    const int ng = n0 + row;
    const size_t nb = (size_t)(ng >> 10) * XT_BSTRIDE +
                      (size_t)(((ng >> 5) & 31) * 2) * XT_HSTRIDE + (size_t)(ng & 31) * 256;
    bG[s] = xT + nb + skq;
    ldsOff[s] = (s * 64 + wave * 16) * 32;
  }

  f32x4 acc[4][4];
#pragma unroll
  for (int i = 0; i < 4; ++i)
#pragma unroll
    for (int j = 0; j < 4; ++j) acc[i][j] = (f32x4){0.f, 0.f, 0.f, 0.f};

  // fragment read: row = tile*16 + (lane&15), k = (lane>>4)*8
  const int frow = (lane & 15) * 32 + (lane >> 4) * 8;

  // B global k-offset for step t  (k = p*256 + (t&7)*32, p = kh*9+kw)
  auto koffB = [](int t) {
    const int p = t >> 3;
    const int kh = p / 9;
    const int kw = p - kh * 9;
    return kh * XT_HSTRIDE + (kw & 1) * 9216 + (kw >> 1) * 256 + (t & 7) * 32;
  };

  // prime buffer 0 with step 0 (koffB(0) == 0)
#pragma unroll
  for (int s = 0; s < 2; ++s) {
    glds16(aG[s], &As[0][ldsOff[s]]);
    glds16(bG[s], &Bs[0][ldsOff[s]]);
  }
  __syncthreads();

  for (int t = 0; t < K_STEPS; ++t) {
    const int cur = t & 1;
    const int nxt = cur ^ 1;
    if (t + 1 < K_STEPS) {
      const int ka = (t + 1) * 32;
      const int kb = koffB(t + 1);
#pragma unroll
      for (int s = 0; s < 2; ++s) {
        glds16(aG[s] + ka, &As[nxt][ldsOff[s]]);
        glds16(bG[s] + kb, &Bs[nxt][ldsOff[s]]);
      }
    }
    short8 af[4], bf[4];
#pragma unroll
    for (int i = 0; i < 4; ++i) af[i] = *(const short8*)&As[cur][(wm * 64 + i * 16) * 32 + frow];
#pragma unroll
    for (int j = 0; j < 4; ++j) bf[j] = *(const short8*)&Bs[cur][(wn * 64 + j * 16) * 32 + frow];
#pragma unroll
    for (int i = 0; i < 4; ++i)
#pragma unroll
      for (int j = 0; j < 4; ++j)
        acc[i][j] = __builtin_amdgcn_mfma_f32_16x16x32_bf16(af[i], bf[j], acc[i][j], 0, 0, 0);
    __syncthreads();
  }

  // C/D 16x16: col = lane&15 (n-local), row = (lane>>4)*4 + reg (m-local)
  // regs 0..3 are m-consecutive -> pack into one 8B store to U[n][m].
  const int cn = lane & 15;
  const int r0 = (lane >> 4) * 4;
#pragma unroll
  for (int i = 0; i < 4; ++i) {
    const int mg = m0 + wm * 64 + i * 16 + r0;
#pragma unroll
    for (int j = 0; j < 4; ++j) {
      const int ng = n0 + wn * 64 + j * 16 + cn;
      uint2 pk;
      pk.x = (uint32_t)f2bf(acc[i][j][0]) | ((uint32_t)f2bf(acc[i][j][1]) << 16);
      pk.y = (uint32_t)f2bf(acc[i][j][2]) | ((uint32_t)f2bf(acc[i][j][3]) << 16);
      *(uint2*)(U + (size_t)ng * M_TOT + mg) = pk;
    }
  }
}

// ---- dynamic routing: one block per (b,hp); thread = (nc,oc) ----
// U is [n][m]: per-wp loads are fully coalesced across the 1024 threads.
__global__ __launch_bounds__(1024) void routing_k(const u16* __restrict__ U,
                                                  const float* __restrict__ bias,
                                                  float* __restrict__ out) {
  const int t = threadIdx.x;       // m = nc*32 + oc
  const int bx = blockIdx.x;
  const int b = bx >> 5;
  const int hp = bx & 31;
  const int oc = t & 31;
  const int nc = t >> 5;
  __shared__ float sm[1024];

  float u_r[32];
  {
    const u16* ub = U + (size_t)(b * 1024 + hp * 32) * M_TOT + t;
    const float bs = bias[t];
#pragma unroll
    for (int w = 0; w < 32; ++w) u_r[w] = bf2f(ub[(size_t)w * M_TOT]) + bs;
  }

  float bij = 0.f;
  float s[32];
  float scale = 0.f;

  for (int it = 0; it < 3; ++it) {
    sm[t] = bij;
    __syncthreads();
    // softmax over nc for this oc (values are small; no max-subtract needed)
    float den = 0.f;
#pragma unroll
    for (int i = 0; i < 32; ++i) den += __expf(sm[i * 32 + oc]);
    const float c = __expf(bij) / den;
    // s[nc][wp] = sum_oc c*u_hat : butterfly allreduce across the 32-lane oc group
#pragma unroll
    for (int w = 0; w < 32; ++w) s[w] = c * u_r[w];
#pragma unroll
    for (int off = 1; off < 32; off <<= 1) {
#pragma unroll
      for (int w = 0; w < 32; ++w) s[w] += __shfl_xor(s[w], off, 64);
    }
    // squash over wp
    float n2 = 0.f;
#pragma unroll
    for (int w = 0; w < 32; ++w) n2 += s[w] * s[w];
    scale = sqrtf(n2) / (1.f + n2);
    if (it < 2) {
      // b_ij += sum_wp u_hat * v ;  v = scale*s
      float agr = 0.f;
#pragma unroll
      for (int w = 0; w < 32; ++w) agr += u_r[w] * s[w];
      bij += scale * agr;
    }
    __syncthreads();
  }

  // lane oc writes element wp==oc (register-select to avoid scratch)
  float val = s[0];
#pragma unroll
  for (int i = 1; i < 32; ++i) val = (oc == i) ? s[i] : val;
  out[(size_t)((b * 32 + nc) * 32 + hp) * 32 + oc] = scale * val;
}

extern "C" void kernel_launch(void* const* d_in, const int* in_sizes, int n_in,
                              void* d_out, int out_size, void* d_ws, size_t ws_size,
                              hipStream_t stream) {
  const float* x = (const float*)d_in[0];
  const float* W = (const float*)d_in[1];
  const float* bias = (const float*)d_in[2];

  // workspace layout (bytes): Wb 42,467,328 | xT 83,755,008 | U 67,108,864  (total 193.3 MB)
  u16* Wb = (u16*)d_ws;
  u16* xT = (u16*)((char*)d_ws + 42467328u);
  u16* U  = (u16*)((char*)d_ws + 126222336u);
  float* out = (float*)d_out;

  pack_w<<<dim3(1024), dim3(256), 0, stream>>>(W, Wb);
  pack_x<<<dim3(71, 32), dim3(256), 0, stream>>>(x, xT);
  conv_gemm<<<dim3(2048), dim3(256), 0, stream>>>(Wb, xT, U);
  routing_k<<<dim3(1024), dim3(1024), 0, stream>>>(U, bias, out);
}